// Round 8
// baseline (463.550 us; speedup 1.0000x reference)
//
#include <hip/hip_runtime.h>
#include <hip/hip_cooperative_groups.h>
#include <math.h>

namespace cg = cooperative_groups;

#define NB  4
#define NLQ 256
#define NLK 512
#define NH  256

// scale folded into projections: exp2(SC*(q+k)) = exp(2*(q+k))
#define SCALE_2LOG2E 2.885390081777927f
#define LOG2E        1.4426950408889634f

// ---------------------------------------------------------------------------
// One cooperative kernel, 512 blocks x 512 threads (2 blocks/CU co-resident).
// Block blk: batch b=blk>>7, q rows q0=(blk&127)*2, k-proj slots 4*(blk&127).
// Phase 0: per-block mask compaction (own batch) + W transposes (blocks 0-31)
// Phase 1: project own 2 q rows -> LDS qv[c]={q0',q1',v}; 4 k slots -> kp_ct
// Phase 2: scores, thread t: slot group 4p..4p+3 (p=t&127), c-quarter t>>7.
//          float4 coalesced kp_ct loads, 8 acc chains, wave-uniform na-skip.
// Phase 3: softmax + out_w scatter.  Phase 4: output GEMV, h-split + combine.
// score'(q,k) = -2*sum_h v[h]*rcp(exp2(q'+k')+1)  (softmax shift-invariant)
// ---------------------------------------------------------------------------
__global__ __launch_bounds__(512, 4) void fused_kernel(
    const float* __restrict__ query, const float* __restrict__ key,
    const float* __restrict__ value, const int* __restrict__ mask,
    const float* __restrict__ Wq, const float* __restrict__ bq,
    const float* __restrict__ Wk, const float* __restrict__ bk,
    const float* __restrict__ vvec,
    float* __restrict__ Wtq, float* __restrict__ Wtk,
    float* __restrict__ kp_ct,
    float* __restrict__ out_o, float* __restrict__ out_w)
{
    __shared__ float  ts[64][65];          // transpose tile / phase-4 partials
    __shared__ float4 qv[NH];              // {q0', q1', v[h], -} per c
    __shared__ float  kcomb[2][NH];        // k-proj c-half partials / phase-4
    __shared__ float  sc0[NLK], sc1[NLK];  // scores -> weights
    __shared__ int    actl[NLK];
    __shared__ int    wcnt[8], wpre[9];
    __shared__ float4 ps0[512], ps1[512];  // score partials (c-quarters)

    cg::grid_group grid = cg::this_grid();

    const int blk  = blockIdx.x;
    const int b    = blk >> 7;
    const int q0   = (blk & 127) * 2;
    const int t    = threadIdx.x;          // 0..511
    const int lane = t & 63;
    const int wave = t >> 6;

    // ================= Phase 0: compaction + transpose =================
    const int mk = mask[b * NLK + t];
    actl[t] = 0;
    const unsigned long long bal = __ballot(mk != 0);
    const int rank = __popcll(bal & ((1ULL << lane) - 1ULL));
    if (lane == 0) wcnt[wave] = __popcll(bal);
    __syncthreads();
    if (t == 0) {
        int s = 0;
        #pragma unroll
        for (int w = 0; w < 8; ++w) { wpre[w] = s; s += wcnt[w]; }
        wpre[8] = s;
    }
    __syncthreads();
    const int na = wpre[8];
    if (mk) actl[wpre[wave] + rank] = t;
    // zero masked out_w slots (softmax scatter fills active ones)
    float* w0row = out_w + (size_t)(b * NLQ + q0) * NLK;
    float* w1row = w0row + NLK;
    if (!mk) { w0row[t] = 0.f; w1row[t] = 0.f; }
    __syncthreads();

    if (blk < 32) {   // block-uniform: transpose one 64x64 tile of Wq/Wk
        const int m    = blk >> 4;
        const int tile = blk & 15;
        const int h0 = (tile >> 2) * 64;
        const int c0 = (tile & 3) * 64;
        const float* W  = m ? Wk  : Wq;
        float*       Wt = m ? Wtk : Wtq;
        #pragma unroll
        for (int i = 0; i < 2; ++i) {
            const int lin = t + 512 * i;
            const int r  = lin >> 4;
            const int c4 = lin & 15;
            const float4 d = *(const float4*)(W + (size_t)(h0 + r) * NH + c0 + c4 * 4);
            ts[r][c4 * 4 + 0] = d.x;
            ts[r][c4 * 4 + 1] = d.y;
            ts[r][c4 * 4 + 2] = d.z;
            ts[r][c4 * 4 + 3] = d.w;
        }
        __syncthreads();
        #pragma unroll
        for (int i = 0; i < 2; ++i) {
            const int lin = t + 512 * i;
            const int c  = lin >> 4;
            const int r4 = lin & 15;
            float4 d;
            d.x = ts[r4 * 4 + 0][c];
            d.y = ts[r4 * 4 + 1][c];
            d.z = ts[r4 * 4 + 2][c];
            d.w = ts[r4 * 4 + 3][c];
            *(float4*)(Wt + (size_t)(c0 + c) * NH + h0 + r4 * 4) = d;
        }
    }
    __threadfence();
    grid.sync();

    // ================= Phase 1: projections =================
    {   // q: thread t -> row r=t>>8, col h=t&255 (coalesced Wtq, uniform x)
        const int r = t >> 8, h = t & 255;
        const float* xr = query + (size_t)(b * NLQ + q0 + r) * NH;
        float a0 = 0.f, a1 = 0.f;
        #pragma unroll 4
        for (int c = 0; c < NH; c += 2) {
            a0 = fmaf(xr[c],     Wtq[(size_t)c * NH + h],       a0);
            a1 = fmaf(xr[c + 1], Wtq[(size_t)(c + 1) * NH + h], a1);
        }
        const float qpv = (a0 + a1 + bq[h]) * SCALE_2LOG2E;
        if (r == 0) { qv[h].x = qpv; qv[h].z = vvec[h]; }
        else        { qv[h].y = qpv; }
    }
    // k: 4 compact slots j0..j0+3 (c-split across thread halves)
    const int j0 = (blk & 127) * 4;
    for (int s = 0; s < 4; ++s) {
        const int j = j0 + s;              // block-uniform guard
        if (j < na) {
            const int kidx = actl[j];
            const float* kr = key + (size_t)(b * NLK + kidx) * NH;
            const int ch = t >> 8, h = t & 255;
            const int cb2 = ch * 128;
            float p0 = 0.f, p1 = 0.f;
            #pragma unroll 4
            for (int c = cb2; c < cb2 + 128; c += 2) {
                p0 = fmaf(kr[c],     Wtk[(size_t)c * NH + h],       p0);
                p1 = fmaf(kr[c + 1], Wtk[(size_t)(c + 1) * NH + h], p1);
            }
            kcomb[ch][h] = p0 + p1;
        }
        __syncthreads();
        if (j < na && t < 256)
            kp_ct[((size_t)b * NH + t) * NLK + j] =
                (kcomb[0][t] + kcomb[1][t] + bk[t]) * SCALE_2LOG2E;
        __syncthreads();
    }
    __threadfence();
    grid.sync();

    // ================= Phase 2: scores =================
    const int p4 = (t & 127) * 4;          // slot group 4p..4p+3
    const int cb = (t >> 7) * 64;          // c-quarter (wave-uniform)
    float a00 = 0.f, a01 = 0.f, a02 = 0.f, a03 = 0.f;
    float a10 = 0.f, a11 = 0.f, a12 = 0.f, a13 = 0.f;
    if (p4 < na) {                         // wave-uniform skip (halves work)
        const float* kb = kp_ct + (size_t)b * NH * NLK + p4;
        #pragma unroll 2
        for (int cc = 0; cc < 64; ++cc) {
            const int c = cb + cc;
            const float4 kx = *(const float4*)(kb + (size_t)c * NLK); // 16B/lane coalesced
            const float4 q  = qv[c];       // same-addr LDS broadcast
            float e;
            e = __builtin_amdgcn_exp2f(q.x + kx.x); a00 = fmaf(q.z, __builtin_amdgcn_rcpf(e + 1.f), a00);
            e = __builtin_amdgcn_exp2f(q.x + kx.y); a01 = fmaf(q.z, __builtin_amdgcn_rcpf(e + 1.f), a01);
            e = __builtin_amdgcn_exp2f(q.x + kx.z); a02 = fmaf(q.z, __builtin_amdgcn_rcpf(e + 1.f), a02);
            e = __builtin_amdgcn_exp2f(q.x + kx.w); a03 = fmaf(q.z, __builtin_amdgcn_rcpf(e + 1.f), a03);
            e = __builtin_amdgcn_exp2f(q.y + kx.x); a10 = fmaf(q.z, __builtin_amdgcn_rcpf(e + 1.f), a10);
            e = __builtin_amdgcn_exp2f(q.y + kx.y); a11 = fmaf(q.z, __builtin_amdgcn_rcpf(e + 1.f), a11);
            e = __builtin_amdgcn_exp2f(q.y + kx.z); a12 = fmaf(q.z, __builtin_amdgcn_rcpf(e + 1.f), a12);
            e = __builtin_amdgcn_exp2f(q.y + kx.w); a13 = fmaf(q.z, __builtin_amdgcn_rcpf(e + 1.f), a13);
        }
    }
    ps0[t] = make_float4(a00, a01, a02, a03);
    ps1[t] = make_float4(a10, a11, a12, a13);
    __syncthreads();
    if (t < 128) {                         // combine 4 c-quarters
        const float4 u0 = ps0[t], u1 = ps0[t + 128], u2 = ps0[t + 256], u3 = ps0[t + 384];
        const float4 v0 = ps1[t], v1 = ps1[t + 128], v2 = ps1[t + 256], v3 = ps1[t + 384];
        const int jj = 4 * t;
        const float s00 = u0.x + u1.x + u2.x + u3.x;
        const float s01 = u0.y + u1.y + u2.y + u3.y;
        const float s02 = u0.z + u1.z + u2.z + u3.z;
        const float s03 = u0.w + u1.w + u2.w + u3.w;
        const float s10 = v0.x + v1.x + v2.x + v3.x;
        const float s11 = v0.y + v1.y + v2.y + v3.y;
        const float s12 = v0.z + v1.z + v2.z + v3.z;
        const float s13 = v0.w + v1.w + v2.w + v3.w;
        sc0[jj + 0] = (jj + 0 < na) ? -2.f * s00 : -INFINITY;
        sc0[jj + 1] = (jj + 1 < na) ? -2.f * s01 : -INFINITY;
        sc0[jj + 2] = (jj + 2 < na) ? -2.f * s02 : -INFINITY;
        sc0[jj + 3] = (jj + 3 < na) ? -2.f * s03 : -INFINITY;
        sc1[jj + 0] = (jj + 0 < na) ? -2.f * s10 : -INFINITY;
        sc1[jj + 1] = (jj + 1 < na) ? -2.f * s11 : -INFINITY;
        sc1[jj + 2] = (jj + 2 < na) ? -2.f * s12 : -INFINITY;
        sc1[jj + 3] = (jj + 3 < na) ? -2.f * s13 : -INFINITY;
    }
    __syncthreads();

    // ================= Phase 3: softmax =================
    if (wave < 2) {
        float* row = wave ? sc1 : sc0;
        float vals[8];
        float m = -INFINITY;
        #pragma unroll
        for (int j8 = 0; j8 < 8; ++j8) {
            vals[j8] = row[lane + j8 * 64];
            m = fmaxf(m, vals[j8]);
        }
        #pragma unroll
        for (int s = 32; s >= 1; s >>= 1)
            m = fmaxf(m, __shfl_xor(m, s, 64));
        float sum = 0.0f;
        #pragma unroll
        for (int j8 = 0; j8 < 8; ++j8) {
            vals[j8] = __builtin_amdgcn_exp2f((vals[j8] - m) * LOG2E);
            sum += vals[j8];
        }
        #pragma unroll
        for (int s = 32; s >= 1; s >>= 1)
            sum += __shfl_xor(sum, s, 64);
        const float inv = __builtin_amdgcn_rcpf(sum);
        float* wout = out_w + (size_t)(b * NLQ + q0 + wave) * NLK;
        #pragma unroll
        for (int j8 = 0; j8 < 8; ++j8) {
            const int jj = lane + j8 * 64;
            const float w = vals[j8] * inv;
            row[jj] = w;                      // 0 for jj >= na
            if (jj < na) wout[actl[jj]] = w;  // masked slots stay 0
        }
    }
    __syncthreads();

    // ================= Phase 4: output =================
    float* ph0 = &kcomb[0][0];             // reuse (512 floats)
    float* ph1 = &ts[0][0];                // reuse (512 of 4160 floats)
    {
        const int h    = t & 255;
        const int half = t >> 8;
        const int n4   = (na + 3) >> 2;
        const int lo   = half * 64;
        const int hi   = (n4 < lo + 64) ? n4 : (lo + 64);
        const float* vb = value + (size_t)b * NLK * NH + h;
        float o0 = 0.f, o1 = 0.f;
        for (int j4 = lo; j4 < hi; ++j4) {
            const float4 w0 = ((const float4*)sc0)[j4];   // LDS broadcast
            const float4 w1 = ((const float4*)sc1)[j4];
            const int4   aj = ((const int4*)actl)[j4];
            const float v0 = vb[(size_t)aj.x * NH];       // coalesced over h
            const float v1 = vb[(size_t)aj.y * NH];
            const float v2 = vb[(size_t)aj.z * NH];
            const float v3 = vb[(size_t)aj.w * NH];
            o0 = fmaf(w0.x, v0, o0); o1 = fmaf(w1.x, v0, o1);
            o0 = fmaf(w0.y, v1, o0); o1 = fmaf(w1.y, v1, o1);
            o0 = fmaf(w0.z, v2, o0); o1 = fmaf(w1.z, v2, o1);
            o0 = fmaf(w0.w, v3, o0); o1 = fmaf(w1.w, v3, o1);
        }
        __syncthreads();                   // ph0/ph1 reuse of kcomb/ts
        ph0[t] = o0;
        ph1[t] = o1;
    }
    __syncthreads();
    if (t < 256) {
        out_o[(size_t)(b * NLQ + q0)     * NH + t] = ph0[t] + ph0[t + 256];
        out_o[(size_t)(b * NLQ + q0 + 1) * NH + t] = ph1[t] + ph1[t + 256];
    }
}

// ---------------------------------------------------------------------------
extern "C" void kernel_launch(void* const* d_in, const int* in_sizes, int n_in,
                              void* d_out, int out_size, void* d_ws, size_t ws_size,
                              hipStream_t stream) {
    const float* query = (const float*)d_in[0];
    const float* key   = (const float*)d_in[1];
    const float* value = (const float*)d_in[2];
    const int*   mask  = (const int*)  d_in[3];
    const float* Wq    = (const float*)d_in[4];
    const float* bq    = (const float*)d_in[5];
    const float* Wk    = (const float*)d_in[6];
    const float* bk    = (const float*)d_in[7];
    const float* v     = (const float*)d_in[8];
    // d_in[9] (bv) drops out of softmax -> unused

    float* out_o = (float*)d_out;                 // [4,256,256]
    float* out_w = out_o + NB * NLQ * NH;         // [4,256,512]

    float* kp_ct = (float*)d_ws;                  // [4,256,512] compact-T, 2MB
    float* wtq   = kp_ct + (size_t)NB * NH * NLK; // 256KB
    float* wtk   = wtq + NH * NH;                 // 256KB

    void* args[] = {
        (void*)&query, (void*)&key, (void*)&value, (void*)&mask,
        (void*)&Wq, (void*)&bq, (void*)&Wk, (void*)&bk, (void*)&v,
        (void*)&wtq, (void*)&wtk, (void*)&kp_ct,
        (void*)&out_o, (void*)&out_w
    };
    hipLaunchCooperativeKernel((const void*)fused_kernel,
                               dim3(NB * NLQ / 2), dim3(512),
                               args, 0, stream);
}

// Round 9
// 135.147 us; speedup vs baseline: 3.4300x; 3.4300x over previous
//
#include <hip/hip_runtime.h>
#include <math.h>

#define NB  4
#define NLQ 256
#define NLK 512
#define NH  256

// scale folded into projections: exp2(SC*(q+k)) = exp(2*(q+k))
#define SCALE_2LOG2E 2.885390081777927f
#define LOG2E        1.4426950408889634f

// ---------------------------------------------------------------------------
// Setup: W transposes (blocks 0..31) + per-batch mask compaction (32..35).
// ---------------------------------------------------------------------------
__global__ __launch_bounds__(256) void setup_kernel(
    const float* __restrict__ Wq, const float* __restrict__ Wk,
    const int* __restrict__ mask,
    float* __restrict__ Wtq, float* __restrict__ Wtk,
    int* __restrict__ act, int* __restrict__ nact)
{
    const int blk = blockIdx.x;
    const int t   = threadIdx.x;

    if (blk < 32) {
        __shared__ float ts[64][65];
        const int m    = blk >> 4;               // 0: Wq, 1: Wk
        const int tile = blk & 15;
        const int h0 = (tile >> 2) * 64;
        const int c0 = (tile & 3) * 64;
        const float* W  = m ? Wk  : Wq;
        float*       Wt = m ? Wtk : Wtq;
        const int lr = t >> 4, lc = t & 15;
        #pragma unroll
        for (int i = 0; i < 4; ++i) {
            const int r = lr + 16 * i;
            const float4 d = *(const float4*)(W + (size_t)(h0 + r) * NH + c0 + lc * 4);
            ts[r][lc * 4 + 0] = d.x;
            ts[r][lc * 4 + 1] = d.y;
            ts[r][lc * 4 + 2] = d.z;
            ts[r][lc * 4 + 3] = d.w;
        }
        __syncthreads();
        #pragma unroll
        for (int i = 0; i < 4; ++i) {
            const int c = lr + 16 * i;
            float4 d;
            d.x = ts[lc * 4 + 0][c];
            d.y = ts[lc * 4 + 1][c];
            d.z = ts[lc * 4 + 2][c];
            d.w = ts[lc * 4 + 3][c];
            *(float4*)(Wt + (size_t)(c0 + c) * NH + h0 + lc * 4) = d;
        }
    } else if (blk < 32 + NB) {
        const int b = blk - 32;
        __shared__ int wcnt[8], wpre[9];
        const int lane = t & 63, wave = t >> 6;
        const int k1 = t, k2 = t + 256;
        const int m1 = mask[b * NLK + k1];
        const int m2 = mask[b * NLK + k2];
        const unsigned long long below = (1ULL << lane) - 1ULL;
        const unsigned long long bal1 = __ballot(m1 != 0);
        const unsigned long long bal2 = __ballot(m2 != 0);
        const int r1 = __popcll(bal1 & below);
        const int r2 = __popcll(bal2 & below);
        if (lane == 0) { wcnt[wave] = __popcll(bal1); wcnt[4 + wave] = __popcll(bal2); }
        __syncthreads();
        if (t == 0) {
            int s = 0;
            #pragma unroll
            for (int w = 0; w < 8; ++w) { wpre[w] = s; s += wcnt[w]; }
            wpre[8] = s;
        }
        __syncthreads();
        const int na = wpre[8];
        if (m1) act[b * NLK + wpre[wave]     + r1] = k1;
        if (m2) act[b * NLK + wpre[4 + wave] + r2] = k2;
        if (k1 >= na) act[b * NLK + k1] = 0;     // safe tail
        if (k2 >= na) act[b * NLK + k2] = 0;
        if (t == 0) nact[b] = na;
    }
}

// ---------------------------------------------------------------------------
// Fused projections (c-split across waves, coalesced Wt loads) — round-6.
// Blocks 0..255: q rows (4/block) -> qp (scaled).
// Blocks 256..767: compact k slots (4/block, gathered via act) -> kp_ct
//   [b][h][j] compact-TRANSPOSED (scaled), so attn reads coalesce.
// ---------------------------------------------------------------------------
__global__ __launch_bounds__(256) void prep_kernel(
    const float* __restrict__ query, const float* __restrict__ key,
    const float* __restrict__ Wtq, const float* __restrict__ bq,
    const float* __restrict__ Wtk, const float* __restrict__ bk,
    const int* __restrict__ act, const int* __restrict__ nact,
    float* __restrict__ qp, float* __restrict__ kp_ct)
{
    const int blk  = blockIdx.x;
    const int t    = threadIdx.x;
    const int wave = t >> 6;
    const int lane = t & 63;

    __shared__ float  xs[4][NH];
    __shared__ float4 ps[4][4][64];
    __shared__ int    ridx[4];

    const float *Wt, *bias;
    int b = 0, j0 = 0, r0 = 0, na = 0;
    const bool isq = (blk < NB * NLQ / 4);

    if (isq) {
        r0 = blk * 4;
        ((float4*)&xs[0][0])[t] = ((const float4*)(query + (size_t)r0 * NH))[t];
        Wt = Wtq; bias = bq;
    } else {
        b  = (blk - 256) >> 7;
        j0 = ((blk - 256) & 127) * 4;
        na = nact[b];
        if (j0 >= na) return;
        if (t < 4) ridx[t] = act[b * NLK + ((j0 + t < na) ? (j0 + t) : j0)];
        __syncthreads();
        const int r = t >> 6, c4 = t & 63;
        ((float4*)xs[r])[c4] =
            ((const float4*)(key + ((size_t)b * NLK + ridx[r]) * NH))[c4];
        Wt = Wtk; bias = bk;
    }
    __syncthreads();

    float4 acc[4];
    #pragma unroll
    for (int r = 0; r < 4; ++r) acc[r] = (float4){0.f, 0.f, 0.f, 0.f};

    const int cbase = wave * 64;
    #pragma unroll 4
    for (int cc = 0; cc < 64; ++cc) {
        const int c = cbase + cc;
        const float4 w = *(const float4*)(Wt + (size_t)c * NH + lane * 4);
        #pragma unroll
        for (int r = 0; r < 4; ++r) {
            const float xv = xs[r][c];             // LDS broadcast
            acc[r].x = fmaf(xv, w.x, acc[r].x);
            acc[r].y = fmaf(xv, w.y, acc[r].y);
            acc[r].z = fmaf(xv, w.z, acc[r].z);
            acc[r].w = fmaf(xv, w.w, acc[r].w);
        }
    }
    #pragma unroll
    for (int r = 0; r < 4; ++r) ps[wave][r][lane] = acc[r];
    __syncthreads();

    const int r = wave, l = lane;
    const float4 p0 = ps[0][r][l], p1 = ps[1][r][l];
    const float4 p2 = ps[2][r][l], p3 = ps[3][r][l];
    const float4 bb = *(const float4*)(bias + l * 4);
    float4 o;
    o.x = (p0.x + p1.x + p2.x + p3.x + bb.x) * SCALE_2LOG2E;
    o.y = (p0.y + p1.y + p2.y + p3.y + bb.y) * SCALE_2LOG2E;
    o.z = (p0.z + p1.z + p2.z + p3.z + bb.z) * SCALE_2LOG2E;
    o.w = (p0.w + p1.w + p2.w + p3.w + bb.w) * SCALE_2LOG2E;

    if (isq) {
        *(float4*)(qp + (size_t)(r0 + r) * NH + l * 4) = o;
    } else if (j0 + r < na) {
        const int j = j0 + r;
        kp_ct[((size_t)b * NH + l * 4 + 0) * NLK + j] = o.x;
        kp_ct[((size_t)b * NH + l * 4 + 1) * NLK + j] = o.y;
        kp_ct[((size_t)b * NH + l * 4 + 2) * NLK + j] = o.z;
        kp_ct[((size_t)b * NH + l * 4 + 3) * NLK + j] = o.w;
    }
}

// ---------------------------------------------------------------------------
// Fused attn. Grid = 1024 (one q row per block), block = 512 threads
// (8 waves) -> 4 blocks/CU = 32 waves/CU (full) at VGPR<=64.
// Scores: thread t = slot pair {2(t&127), +1} (float2 coalesced kp_ct)
// over c-quarter (t>>7)*64; quarters combined via LDS. Mask-skip: only
// slots < na computed; overflow (na>256) via guarded pass 2.
// score'(q,k) = -2*sum_h v[h]*rcp(exp2(q'+k')+1)  (softmax shift-invariant)
// ---------------------------------------------------------------------------
__global__ __launch_bounds__(512, 8) void attn_kernel(
    const float* __restrict__ qp, const float* __restrict__ kp_ct,
    const float* __restrict__ value, const int* __restrict__ mask,
    const int* __restrict__ act, const int* __restrict__ nact,
    const float* __restrict__ vvec,
    float* __restrict__ out_o, float* __restrict__ out_w)
{
    __shared__ __align__(16) float  sc[NLK];
    __shared__ __align__(16) int    actl[NLK];
    __shared__ float2 qv[NH];            // {q', v}
    __shared__ float2 ps[512];           // score partials
    __shared__ float  ph[512];           // output partials

    const int blk  = blockIdx.x;
    const int b    = blk >> 8;           // 256 blocks per batch
    const int q    = blk & 255;
    const int t    = threadIdx.x;        // 0..511
    const int lane = t & 63;
    const int wave = t >> 6;

    const int na = nact[b];
    actl[t] = act[b * NLK + t];          // safe 0 tail from setup

    if (t < NH)
        qv[t] = make_float2(qp[(size_t)(b * NLQ + q) * NH + t], vvec[t]);
    float* wrow = out_w + (size_t)(b * NLQ + q) * NLK;
    if (!mask[b * NLK + t]) wrow[t] = 0.f;   // masked slots -> 0
    __syncthreads();

    // ---- scores: pass 1, slots 0..255 ----
    const int p  = t & 127;
    const int cb = (t >> 7) * 64;        // c-quarter (wave-uniform)
    const float* kb = kp_ct + (size_t)b * NH * NLK + 2 * p;
    float a0 = 0.f, a1 = 0.f;
    if (2 * p < na) {
        #pragma unroll 4
        for (int cc = 0; cc < 64; ++cc) {
            const int c = cb + cc;
            const float2 kx = *(const float2*)(kb + (size_t)c * NLK); // 8B/lane coalesced
            const float2 q2 = qv[c];                                  // same-addr broadcast
            float e;
            e = __builtin_amdgcn_exp2f(q2.x + kx.x);
            a0 = fmaf(q2.y, __builtin_amdgcn_rcpf(e + 1.f), a0);
            e = __builtin_amdgcn_exp2f(q2.x + kx.y);
            a1 = fmaf(q2.y, __builtin_amdgcn_rcpf(e + 1.f), a1);
        }
    }
    ps[t] = make_float2(a0, a1);
    __syncthreads();
    if (t < 128) {
        const float2 u0 = ps[t], u1 = ps[t + 128], u2 = ps[t + 256], u3 = ps[t + 384];
        const int s = 2 * t;
        sc[s]     = (s     < na) ? -2.f * (u0.x + u1.x + u2.x + u3.x) : -INFINITY;
        sc[s + 1] = (s + 1 < na) ? -2.f * (u0.y + u1.y + u2.y + u3.y) : -INFINITY;
    }

    // ---- scores: pass 2, overflow slots 256..na (block-uniform branch) ----
    if (na > 256) {
        float b0 = 0.f, b1 = 0.f;
        const int s0 = 256 + 2 * p;
        if (s0 < na) {                   // waves w/o active lanes: execz skip
            const float* kb2 = kp_ct + (size_t)b * NH * NLK + s0;
            #pragma unroll 4
            for (int cc = 0; cc < 64; ++cc) {
                const int c = cb + cc;
                const float2 kx = *(const float2*)(kb2 + (size_t)c * NLK);
                const float2 q2 = qv[c];
                float e;
                e = __builtin_amdgcn_exp2f(q2.x + kx.x);
                b0 = fmaf(q2.y, __builtin_amdgcn_rcpf(e + 1.f), b0);
                e = __builtin_amdgcn_exp2f(q2.x + kx.y);
                b1 = fmaf(q2.y, __builtin_amdgcn_rcpf(e + 1.f), b1);
            }
        }
        __syncthreads();                 // ps reuse
        ps[t] = make_float2(b0, b1);
        __syncthreads();
        if (t < 128) {
            const float2 u0 = ps[t], u1 = ps[t + 128], u2 = ps[t + 256], u3 = ps[t + 384];
            const int s = 256 + 2 * t;
            sc[s]     = (s     < na) ? -2.f * (u0.x + u1.x + u2.x + u3.x) : -INFINITY;
            sc[s + 1] = (s + 1 < na) ? -2.f * (u0.y + u1.y + u2.y + u3.y) : -INFINITY;
        }
    } else {
        if (t < 256) sc[256 + t] = -INFINITY;
    }
    __syncthreads();

    // ---- softmax: wave 0, 8 slots/lane ----
    if (wave == 0) {
        float vals[8];
        float m = -INFINITY;
        #pragma unroll
        for (int j8 = 0; j8 < 8; ++j8) {
            vals[j8] = sc[lane + j8 * 64];
            m = fmaxf(m, vals[j8]);
        }
        #pragma unroll
        for (int s = 32; s >= 1; s >>= 1)
            m = fmaxf(m, __shfl_xor(m, s, 64));
        float sum = 0.0f;
        #pragma unroll
        for (int j8 = 0; j8 < 8; ++j8) {
            vals[j8] = __builtin_amdgcn_exp2f((vals[j8] - m) * LOG2E);
            sum += vals[j8];
        }
        #pragma unroll
        for (int s = 32; s >= 1; s >>= 1)
            sum += __shfl_xor(sum, s, 64);
        const float inv = __builtin_amdgcn_rcpf(sum);
        #pragma unroll
        for (int j8 = 0; j8 < 8; ++j8) {
            const int jj = lane + j8 * 64;
            const float w = vals[j8] * inv;
            sc[jj] = w;                       // 0 for jj >= na
            if (jj < na) wrow[actl[jj]] = w;  // masked slots stay 0
        }
    }
    __syncthreads();

    // ---- output: thread t -> h = t&255, j-half t>>8; LDS combine ----
    {
        const int h    = t & 255;
        const int half = t >> 8;
        const int n4   = (na + 3) >> 2;
        const int lo   = half * 64;
        const int hi   = (n4 < lo + 64) ? n4 : (lo + 64);
        const float* vb = value + (size_t)b * NLK * NH + h;
        float o = 0.f;
        for (int j4 = lo; j4 < hi; ++j4) {
            const float4 w  = ((const float4*)sc)[j4];    // LDS broadcast
            const int4   aj = ((const int4*)actl)[j4];
            o = fmaf(w.x, vb[(size_t)aj.x * NH], o);      // coalesced over h
            o = fmaf(w.y, vb[(size_t)aj.y * NH], o);
            o = fmaf(w.z, vb[(size_t)aj.z * NH], o);
            o = fmaf(w.w, vb[(size_t)aj.w * NH], o);
        }
        ph[t] = o;
    }
    __syncthreads();
    if (t < 256)
        out_o[(size_t)(b * NLQ + q) * NH + t] = ph[t] + ph[t + 256];
}

// ---------------------------------------------------------------------------
extern "C" void kernel_launch(void* const* d_in, const int* in_sizes, int n_in,
                              void* d_out, int out_size, void* d_ws, size_t ws_size,
                              hipStream_t stream) {
    const float* query = (const float*)d_in[0];
    const float* key   = (const float*)d_in[1];
    const float* value = (const float*)d_in[2];
    const int*   mask  = (const int*)  d_in[3];
    const float* Wq    = (const float*)d_in[4];
    const float* bq    = (const float*)d_in[5];
    const float* Wk    = (const float*)d_in[6];
    const float* bk    = (const float*)d_in[7];
    const float* v     = (const float*)d_in[8];
    // d_in[9] (bv) drops out of softmax -> unused

    float* out_o = (float*)d_out;                     // [4,256,256]
    float* out_w = out_o + NB * NLQ * NH;             // [4,256,512]

    float* qp    = (float*)d_ws;                      // [4,256,256] scaled
    float* kp_ct = qp + NB * NLQ * NH;                // [4,256,512] compact-T
    int*   act   = (int*)(kp_ct + NB * NH * NLK);     // [4,512]
    int*   nact  = act + NB * NLK;                    // [4]

    const size_t base = (size_t)(NB * NLQ * NH) + (size_t)(NB * NH * NLK)
                      + NB * NLK + NB;
    float* wtq;
    if (ws_size >= (base + 2 * NH * NH) * sizeof(float)) {
        wtq = (float*)d_ws + base;                    // workspace tail
    } else {
        // park W^T in the out_w tail; attn (after prep) overwrites out_w
        wtq = out_w + (size_t)NB * NLQ * NLK - 2 * NH * NH;
    }
    float* wtk = wtq + NH * NH;

    setup_kernel<<<36, 256, 0, stream>>>(Wq, Wk, mask, wtq, wtk, act, nact);
    prep_kernel<<<NB * NLQ / 4 + NB * NLK / 4, 256, 0, stream>>>(
        query, key, wtq, bq, wtk, bk, act, nact, qp, kp_ct);
    attn_kernel<<<NB * NLQ, 512, 0, stream>>>(
        qp, kp_ct, value, mask, act, nact, v, out_o, out_w);
}

// Round 10
// 130.384 us; speedup vs baseline: 3.5553x; 1.0365x over previous
//
#include <hip/hip_runtime.h>
#include <math.h>

#define NB  4
#define NLQ 256
#define NLK 512
#define NH  256

// scale folded into projections: exp2(SC*(q+k)) = exp(2*(q+k))
#define SCALE_2LOG2E 2.885390081777927f
#define LOG2E        1.4426950408889634f

// ---------------------------------------------------------------------------
// Setup: W transposes (blocks 0..31) + per-batch mask compaction (32..35).
// ---------------------------------------------------------------------------
__global__ __launch_bounds__(256) void setup_kernel(
    const float* __restrict__ Wq, const float* __restrict__ Wk,
    const int* __restrict__ mask,
    float* __restrict__ Wtq, float* __restrict__ Wtk,
    int* __restrict__ act, int* __restrict__ nact)
{
    const int blk = blockIdx.x;
    const int t   = threadIdx.x;

    if (blk < 32) {
        __shared__ float ts[64][65];
        const int m    = blk >> 4;               // 0: Wq, 1: Wk
        const int tile = blk & 15;
        const int h0 = (tile >> 2) * 64;
        const int c0 = (tile & 3) * 64;
        const float* W  = m ? Wk  : Wq;
        float*       Wt = m ? Wtk : Wtq;
        const int lr = t >> 4, lc = t & 15;
        #pragma unroll
        for (int i = 0; i < 4; ++i) {
            const int r = lr + 16 * i;
            const float4 d = *(const float4*)(W + (size_t)(h0 + r) * NH + c0 + lc * 4);
            ts[r][lc * 4 + 0] = d.x;
            ts[r][lc * 4 + 1] = d.y;
            ts[r][lc * 4 + 2] = d.z;
            ts[r][lc * 4 + 3] = d.w;
        }
        __syncthreads();
        #pragma unroll
        for (int i = 0; i < 4; ++i) {
            const int c = lr + 16 * i;
            float4 d;
            d.x = ts[lc * 4 + 0][c];
            d.y = ts[lc * 4 + 1][c];
            d.z = ts[lc * 4 + 2][c];
            d.w = ts[lc * 4 + 3][c];
            *(float4*)(Wt + (size_t)(c0 + c) * NH + h0 + lc * 4) = d;
        }
    } else if (blk < 32 + NB) {
        const int b = blk - 32;
        __shared__ int wcnt[8], wpre[9];
        const int lane = t & 63, wave = t >> 6;
        const int k1 = t, k2 = t + 256;
        const int m1 = mask[b * NLK + k1];
        const int m2 = mask[b * NLK + k2];
        const unsigned long long below = (1ULL << lane) - 1ULL;
        const unsigned long long bal1 = __ballot(m1 != 0);
        const unsigned long long bal2 = __ballot(m2 != 0);
        const int r1 = __popcll(bal1 & below);
        const int r2 = __popcll(bal2 & below);
        if (lane == 0) { wcnt[wave] = __popcll(bal1); wcnt[4 + wave] = __popcll(bal2); }
        __syncthreads();
        if (t == 0) {
            int s = 0;
            #pragma unroll
            for (int w = 0; w < 8; ++w) { wpre[w] = s; s += wcnt[w]; }
            wpre[8] = s;
        }
        __syncthreads();
        const int na = wpre[8];
        if (m1) act[b * NLK + wpre[wave]     + r1] = k1;
        if (m2) act[b * NLK + wpre[4 + wave] + r2] = k2;
        if (k1 >= na) act[b * NLK + k1] = 0;     // safe tail
        if (k2 >= na) act[b * NLK + k2] = 0;
        if (t == 0) nact[b] = na;
    }
}

// ---------------------------------------------------------------------------
// Fused projections (c-split across waves, coalesced Wt loads).
// Blocks 0..255: q rows (4/block) -> qp (scaled).
// Blocks 256..767: compact k slots (4/block, gathered via act) -> kp_ct
//   [b][h][j] compact-TRANSPOSED (scaled), so attn reads coalesce.
// ---------------------------------------------------------------------------
__global__ __launch_bounds__(256) void prep_kernel(
    const float* __restrict__ query, const float* __restrict__ key,
    const float* __restrict__ Wtq, const float* __restrict__ bq,
    const float* __restrict__ Wtk, const float* __restrict__ bk,
    const int* __restrict__ act, const int* __restrict__ nact,
    float* __restrict__ qp, float* __restrict__ kp_ct)
{
    const int blk  = blockIdx.x;
    const int t    = threadIdx.x;
    const int wave = t >> 6;
    const int lane = t & 63;

    __shared__ float  xs[4][NH];
    __shared__ float4 ps[4][4][64];
    __shared__ int    ridx[4];

    const float *Wt, *bias;
    int b = 0, j0 = 0, r0 = 0, na = 0;
    const bool isq = (blk < NB * NLQ / 4);

    if (isq) {
        r0 = blk * 4;
        ((float4*)&xs[0][0])[t] = ((const float4*)(query + (size_t)r0 * NH))[t];
        Wt = Wtq; bias = bq;
    } else {
        b  = (blk - 256) >> 7;
        j0 = ((blk - 256) & 127) * 4;
        na = nact[b];
        if (j0 >= na) return;
        if (t < 4) ridx[t] = act[b * NLK + ((j0 + t < na) ? (j0 + t) : j0)];
        __syncthreads();
        const int r = t >> 6, c4 = t & 63;
        ((float4*)xs[r])[c4] =
            ((const float4*)(key + ((size_t)b * NLK + ridx[r]) * NH))[c4];
        Wt = Wtk; bias = bk;
    }
    __syncthreads();

    float4 acc[4];
    #pragma unroll
    for (int r = 0; r < 4; ++r) acc[r] = (float4){0.f, 0.f, 0.f, 0.f};

    const int cbase = wave * 64;
    #pragma unroll 4
    for (int cc = 0; cc < 64; ++cc) {
        const int c = cbase + cc;
        const float4 w = *(const float4*)(Wt + (size_t)c * NH + lane * 4);
        #pragma unroll
        for (int r = 0; r < 4; ++r) {
            const float xv = xs[r][c];             // LDS broadcast
            acc[r].x = fmaf(xv, w.x, acc[r].x);
            acc[r].y = fmaf(xv, w.y, acc[r].y);
            acc[r].z = fmaf(xv, w.z, acc[r].z);
            acc[r].w = fmaf(xv, w.w, acc[r].w);
        }
    }
    #pragma unroll
    for (int r = 0; r < 4; ++r) ps[wave][r][lane] = acc[r];
    __syncthreads();

    const int r = wave, l = lane;
    const float4 p0 = ps[0][r][l], p1 = ps[1][r][l];
    const float4 p2 = ps[2][r][l], p3 = ps[3][r][l];
    const float4 bb = *(const float4*)(bias + l * 4);
    float4 o;
    o.x = (p0.x + p1.x + p2.x + p3.x + bb.x) * SCALE_2LOG2E;
    o.y = (p0.y + p1.y + p2.y + p3.y + bb.y) * SCALE_2LOG2E;
    o.z = (p0.z + p1.z + p2.z + p3.z + bb.z) * SCALE_2LOG2E;
    o.w = (p0.w + p1.w + p2.w + p3.w + bb.w) * SCALE_2LOG2E;

    if (isq) {
        *(float4*)(qp + (size_t)(r0 + r) * NH + l * 4) = o;
    } else if (j0 + r < na) {
        const int j = j0 + r;
        kp_ct[((size_t)b * NH + l * 4 + 0) * NLK + j] = o.x;
        kp_ct[((size_t)b * NH + l * 4 + 1) * NLK + j] = o.y;
        kp_ct[((size_t)b * NH + l * 4 + 2) * NLK + j] = o.z;
        kp_ct[((size_t)b * NH + l * 4 + 3) * NLK + j] = o.w;
    }
}

// ---------------------------------------------------------------------------
// Fused attn. Grid = 1024 (one q row per block), block = 512 threads
// (8 waves), __launch_bounds__(512,8) -> 4 blocks/CU = 32 waves/CU.
// Scores: lane <-> slot-quad 4*lane (one float4 = 1KB/wave coalesced),
// wave <-> 32-c chunk; inner loop = groups of 4 c with EXPLICITLY BATCHED
// loads (4x float4 kx + 4x float2 qv locals -> ~8 loads in flight/thread),
// 4 independent acc chains. 8-way c-chunk combine via LDS.
// Mask-skip: pass 1 = slots 0..255, guarded pass 2 for na>256.
// score'(q,k) = -2*sum_h v[h]*rcp(exp2(q'+k')+1)  (softmax shift-invariant)
// ---------------------------------------------------------------------------
__global__ __launch_bounds__(512, 8) void attn_kernel(
    const float* __restrict__ qp, const float* __restrict__ kp_ct,
    const float* __restrict__ value, const int* __restrict__ mask,
    const int* __restrict__ act, const int* __restrict__ nact,
    const float* __restrict__ vvec,
    float* __restrict__ out_o, float* __restrict__ out_w)
{
    __shared__ __align__(16) float  sc[NLK];
    __shared__ __align__(16) int    actl[NLK];
    __shared__ float2 qv[NH];            // {q', v}
    __shared__ float4 ps4[512];          // per-thread slot-quad partials
    __shared__ float  ph[512];           // output partials

    const int blk  = blockIdx.x;
    const int b    = blk >> 8;           // 256 blocks per batch
    const int q    = blk & 255;
    const int t    = threadIdx.x;        // 0..511
    const int lane = t & 63;
    const int wave = t >> 6;

    const int na = nact[b];
    actl[t] = act[b * NLK + t];          // safe 0 tail from setup

    if (t < NH)
        qv[t] = make_float2(qp[(size_t)(b * NLQ + q) * NH + t], vvec[t]);
    float* wrow = out_w + (size_t)(b * NLQ + q) * NLK;
    if (!mask[b * NLK + t]) wrow[t] = 0.f;   // masked slots -> 0
    __syncthreads();

    const int cb = wave * 32;            // this wave's c-chunk
    const float* kbase = kp_ct + (size_t)b * NH * NLK + (size_t)cb * NLK;

    // ---- scores pass 1: slot-quad 4*lane (slots 0..255) ----
    float4 acc = {0.f, 0.f, 0.f, 0.f};
    if (4 * lane < na) {
        const float* kptr = kbase + 4 * lane;
        for (int g = 0; g < 8; ++g) {    // 8 groups of 4 c
            // batched loads: 4 float4 global + 4 float2 LDS, all independent
            const float4 kx0 = *(const float4*)(kptr);
            const float4 kx1 = *(const float4*)(kptr + NLK);
            const float4 kx2 = *(const float4*)(kptr + 2 * NLK);
            const float4 kx3 = *(const float4*)(kptr + 3 * NLK);
            const int c0 = cb + 4 * g;
            const float2 q0 = qv[c0], q1 = qv[c0 + 1];
            const float2 q2 = qv[c0 + 2], q3 = qv[c0 + 3];
            float e;
            e = __builtin_amdgcn_exp2f(q0.x + kx0.x); acc.x = fmaf(q0.y, __builtin_amdgcn_rcpf(e + 1.f), acc.x);
            e = __builtin_amdgcn_exp2f(q0.x + kx0.y); acc.y = fmaf(q0.y, __builtin_amdgcn_rcpf(e + 1.f), acc.y);
            e = __builtin_amdgcn_exp2f(q0.x + kx0.z); acc.z = fmaf(q0.y, __builtin_amdgcn_rcpf(e + 1.f), acc.z);
            e = __builtin_amdgcn_exp2f(q0.x + kx0.w); acc.w = fmaf(q0.y, __builtin_amdgcn_rcpf(e + 1.f), acc.w);
            e = __builtin_amdgcn_exp2f(q1.x + kx1.x); acc.x = fmaf(q1.y, __builtin_amdgcn_rcpf(e + 1.f), acc.x);
            e = __builtin_amdgcn_exp2f(q1.x + kx1.y); acc.y = fmaf(q1.y, __builtin_amdgcn_rcpf(e + 1.f), acc.y);
            e = __builtin_amdgcn_exp2f(q1.x + kx1.z); acc.z = fmaf(q1.y, __builtin_amdgcn_rcpf(e + 1.f), acc.z);
            e = __builtin_amdgcn_exp2f(q1.x + kx1.w); acc.w = fmaf(q1.y, __builtin_amdgcn_rcpf(e + 1.f), acc.w);
            e = __builtin_amdgcn_exp2f(q2.x + kx2.x); acc.x = fmaf(q2.y, __builtin_amdgcn_rcpf(e + 1.f), acc.x);
            e = __builtin_amdgcn_exp2f(q2.x + kx2.y); acc.y = fmaf(q2.y, __builtin_amdgcn_rcpf(e + 1.f), acc.y);
            e = __builtin_amdgcn_exp2f(q2.x + kx2.z); acc.z = fmaf(q2.y, __builtin_amdgcn_rcpf(e + 1.f), acc.z);
            e = __builtin_amdgcn_exp2f(q2.x + kx2.w); acc.w = fmaf(q2.y, __builtin_amdgcn_rcpf(e + 1.f), acc.w);
            e = __builtin_amdgcn_exp2f(q3.x + kx3.x); acc.x = fmaf(q3.y, __builtin_amdgcn_rcpf(e + 1.f), acc.x);
            e = __builtin_amdgcn_exp2f(q3.x + kx3.y); acc.y = fmaf(q3.y, __builtin_amdgcn_rcpf(e + 1.f), acc.y);
            e = __builtin_amdgcn_exp2f(q3.x + kx3.z); acc.z = fmaf(q3.y, __builtin_amdgcn_rcpf(e + 1.f), acc.z);
            e = __builtin_amdgcn_exp2f(q3.x + kx3.w); acc.w = fmaf(q3.y, __builtin_amdgcn_rcpf(e + 1.f), acc.w);
            kptr += 4 * NLK;
        }
    }
    ps4[t] = acc;
    __syncthreads();
    if (t < 64) {                        // combine 8 c-chunks, slot-quad t
        float4 s = ps4[t];
        #pragma unroll
        for (int w = 1; w < 8; ++w) {
            const float4 u = ps4[t + 64 * w];
            s.x += u.x; s.y += u.y; s.z += u.z; s.w += u.w;
        }
        const int j = 4 * t;
        sc[j + 0] = (j + 0 < na) ? -2.f * s.x : -INFINITY;
        sc[j + 1] = (j + 1 < na) ? -2.f * s.y : -INFINITY;
        sc[j + 2] = (j + 2 < na) ? -2.f * s.z : -INFINITY;
        sc[j + 3] = (j + 3 < na) ? -2.f * s.w : -INFINITY;
    }

    // ---- scores pass 2: overflow slots 256..na (block-uniform branch) ----
    if (na > 256) {
        float4 acc2 = {0.f, 0.f, 0.f, 0.f};
        const int s0 = 256 + 4 * lane;
        if (s0 < na) {
            const float* kptr = kbase + s0;
            for (int g = 0; g < 8; ++g) {
                const float4 kx0 = *(const float4*)(kptr);
                const float4 kx1 = *(const float4*)(kptr + NLK);
                const float4 kx2 = *(const float4*)(kptr + 2 * NLK);
                const float4 kx3 = *(const float4*)(kptr + 3 * NLK);
                const int c0 = cb + 4 * g;
                const float2 q0 = qv[c0], q1 = qv[c0 + 1];
                const float2 q2 = qv[c0 + 2], q3 = qv[c0 + 3];
                float e;
                e = __builtin_amdgcn_exp2f(q0.x + kx0.x); acc2.x = fmaf(q0.y, __builtin_amdgcn_rcpf(e + 1.f), acc2.x);
                e = __builtin_amdgcn_exp2f(q0.x + kx0.y); acc2.y = fmaf(q0.y, __builtin_amdgcn_rcpf(e + 1.f), acc2.y);
                e = __builtin_amdgcn_exp2f(q0.x + kx0.z); acc2.z = fmaf(q0.y, __builtin_amdgcn_rcpf(e + 1.f), acc2.z);
                e = __builtin_amdgcn_exp2f(q0.x + kx0.w); acc2.w = fmaf(q0.y, __builtin_amdgcn_rcpf(e + 1.f), acc2.w);
                e = __builtin_amdgcn_exp2f(q1.x + kx1.x); acc2.x = fmaf(q1.y, __builtin_amdgcn_rcpf(e + 1.f), acc2.x);
                e = __builtin_amdgcn_exp2f(q1.x + kx1.y); acc2.y = fmaf(q1.y, __builtin_amdgcn_rcpf(e + 1.f), acc2.y);
                e = __builtin_amdgcn_exp2f(q1.x + kx1.z); acc2.z = fmaf(q1.y, __builtin_amdgcn_rcpf(e + 1.f), acc2.z);
                e = __builtin_amdgcn_exp2f(q1.x + kx1.w); acc2.w = fmaf(q1.y, __builtin_amdgcn_rcpf(e + 1.f), acc2.w);
                e = __builtin_amdgcn_exp2f(q2.x + kx2.x); acc2.x = fmaf(q2.y, __builtin_amdgcn_rcpf(e + 1.f), acc2.x);
                e = __builtin_amdgcn_exp2f(q2.x + kx2.y); acc2.y = fmaf(q2.y, __builtin_amdgcn_rcpf(e + 1.f), acc2.y);
                e = __builtin_amdgcn_exp2f(q2.x + kx2.z); acc2.z = fmaf(q2.y, __builtin_amdgcn_rcpf(e + 1.f), acc2.z);
                e = __builtin_amdgcn_exp2f(q2.x + kx2.w); acc2.w = fmaf(q2.y, __builtin_amdgcn_rcpf(e + 1.f), acc2.w);
                e = __builtin_amdgcn_exp2f(q3.x + kx3.x); acc2.x = fmaf(q3.y, __builtin_amdgcn_rcpf(e + 1.f), acc2.x);
                e = __builtin_amdgcn_exp2f(q3.x + kx3.y); acc2.y = fmaf(q3.y, __builtin_amdgcn_rcpf(e + 1.f), acc2.y);
                e = __builtin_amdgcn_exp2f(q3.x + kx3.z); acc2.z = fmaf(q3.y, __builtin_amdgcn_rcpf(e + 1.f), acc2.z);
                e = __builtin_amdgcn_exp2f(q3.x + kx3.w); acc2.w = fmaf(q3.y, __builtin_amdgcn_rcpf(e + 1.f), acc2.w);
                kptr += 4 * NLK;
            }
        }
        __syncthreads();                 // ps4 reuse
        ps4[t] = acc2;
        __syncthreads();
        if (t < 64) {
            float4 s = ps4[t];
            #pragma unroll
            for (int w = 1; w < 8; ++w) {
                const float4 u = ps4[t + 64 * w];
                s.x += u.x; s.y += u.y; s.z += u.z; s.w += u.w;
            }
            const int j = 256 + 4 * t;
            sc[j + 0] = (j + 0 < na) ? -2.f * s.x : -INFINITY;
            sc[j + 1] = (j + 1 < na) ? -2.f * s.y : -INFINITY;
            sc[j + 2] = (j + 2 < na) ? -2.f * s.z : -INFINITY;
            sc[j + 3] = (j + 3 < na) ? -2.f * s.w : -INFINITY;
        }
    } else {
        if (t < 256) sc[256 + t] = -INFINITY;
    }
    __syncthreads();

    // ---- softmax: wave 0, 8 slots/lane ----
    if (wave == 0) {
        float vals[8];
        float m = -INFINITY;
        #pragma unroll
        for (int j8 = 0; j8 < 8; ++j8) {
            vals[j8] = sc[lane + j8 * 64];
            m = fmaxf(m, vals[j8]);
        }
        #pragma unroll
        for (int s = 32; s >= 1; s >>= 1)
            m = fmaxf(m, __shfl_xor(m, s, 64));
        float sum = 0.0f;
        #pragma unroll
        for (int j8 = 0; j8 < 8; ++j8) {
            vals[j8] = __builtin_amdgcn_exp2f((vals[j8] - m) * LOG2E);
            sum += vals[j8];
        }
        #pragma unroll
        for (int s = 32; s >= 1; s >>= 1)
            sum += __shfl_xor(sum, s, 64);
        const float inv = __builtin_amdgcn_rcpf(sum);
        #pragma unroll
        for (int j8 = 0; j8 < 8; ++j8) {
            const int jj = lane + j8 * 64;
            const float w = vals[j8] * inv;
            sc[jj] = w;                       // 0 for jj >= na
            if (jj < na) wrow[actl[jj]] = w;  // masked slots stay 0
        }
    }
    __syncthreads();

    // ---- output: thread t -> h = t&255, j-half t>>8; batched loads ----
    {
        const int h    = t & 255;
        const int half = t >> 8;
        const int n4   = (na + 3) >> 2;
        const int lo   = half * 64;
        const int hi   = (n4 < lo + 64) ? n4 : (lo + 64);
        const float* vb = value + (size_t)b * NLK * NH + h;
        float o = 0.f;
        int j4 = lo;
        for (; j4 + 2 <= hi; j4 += 2) {
            const float4 w0 = ((const float4*)sc)[j4];
            const float4 w1 = ((const float4*)sc)[j4 + 1];
            const int4   a0 = ((const int4*)actl)[j4];
            const int4   a1 = ((const int4*)actl)[j4 + 1];
            const float v0 = vb[(size_t)a0.x * NH];   // 8 batched loads
            const float v1 = vb[(size_t)a0.y * NH];
            const float v2 = vb[(size_t)a0.z * NH];
            const float v3 = vb[(size_t)a0.w * NH];
            const float v4 = vb[(size_t)a1.x * NH];
            const float v5 = vb[(size_t)a1.y * NH];
            const float v6 = vb[(size_t)a1.z * NH];
            const float v7 = vb[(size_t)a1.w * NH];
            o = fmaf(w0.x, v0, o);
            o = fmaf(w0.y, v1, o);
            o = fmaf(w0.z, v2, o);
            o = fmaf(w0.w, v3, o);
            o = fmaf(w1.x, v4, o);
            o = fmaf(w1.y, v5, o);
            o = fmaf(w1.z, v6, o);
            o = fmaf(w1.w, v7, o);
        }
        if (j4 < hi) {
            const float4 w0 = ((const float4*)sc)[j4];
            const int4   a0 = ((const int4*)actl)[j4];
            o = fmaf(w0.x, vb[(size_t)a0.x * NH], o);
            o = fmaf(w0.y, vb[(size_t)a0.y * NH], o);
            o = fmaf(w0.z, vb[(size_t)a0.z * NH], o);
            o = fmaf(w0.w, vb[(size_t)a0.w * NH], o);
        }
        ph[t] = o;
    }
    __syncthreads();
    if (t < 256)
        out_o[(size_t)(b * NLQ + q) * NH + t] = ph[t] + ph[t + 256];
}

// ---------------------------------------------------------------------------
extern "C" void kernel_launch(void* const* d_in, const int* in_sizes, int n_in,
                              void* d_out, int out_size, void* d_ws, size_t ws_size,
                              hipStream_t stream) {
    const float* query = (const float*)d_in[0];
    const float* key   = (const float*)d_in[1];
    const float* value = (const float*)d_in[2];
    const int*   mask  = (const int*)  d_in[3];
    const float* Wq    = (const float*)d_in[4];
    const float* bq    = (const float*)d_in[5];
    const float* Wk    = (const float*)d_in[6];
    const float* bk    = (const float*)d_in[7];
    const float* v     = (const float*)d_in[8];
    // d_in[9] (bv) drops out of softmax -> unused

    float* out_o = (float*)d_out;                     // [4,256,256]
    float* out_w = out_o + NB * NLQ * NH;             // [4,256,512]

    float* qp    = (float*)d_ws;                      // [4,256,256] scaled
    float* kp_ct = qp + NB * NLQ * NH;                // [4,256,512] compact-T
    int*   act   = (int*)(kp_ct + NB * NH * NLK);     // [4,512]
    int*   nact  = act + NB * NLK;                    // [4]

    const size_t base = (size_t)(NB * NLQ * NH) + (size_t)(NB * NH * NLK)
                      + NB * NLK + NB;
    float* wtq;
    if (ws_size >= (base + 2 * NH * NH) * sizeof(float)) {
        wtq = (float*)d_ws + base;                    // workspace tail
    } else {
        // park W^T in the out_w tail; attn (after prep) overwrites out_w
        wtq = out_w + (size_t)NB * NLQ * NLK - 2 * NH * NH;
    }
    float* wtk = wtq + NH * NH;

    setup_kernel<<<36, 256, 0, stream>>>(Wq, Wk, mask, wtq, wtk, act, nact);
    prep_kernel<<<NB * NLQ / 4 + NB * NLK / 4, 256, 0, stream>>>(
        query, key, wtq, bq, wtk, bk, act, nact, qp, kp_ct);
    attn_kernel<<<NB * NLQ, 512, 0, stream>>>(
        qp, kp_ct, value, mask, act, nact, v, out_o, out_w);
}